// Round 14
// baseline (270.683 us; speedup 1.0000x reference)
//
#include <hip/hip_runtime.h>

#define HH 1024
#define WW 1024
#define NB 16
#define NTH 3
#define BAND 64
#define NBAND (HH/BAND)       // 16
#define NSTRIP 11             // strips of 128 cols, 96-col yield
#define ACC_BYTES 4096
#define NEGBIG -1e30f
#define RING 35
#define L10 14.426950408889634f   // 10*log2(e)

typedef unsigned int u32;
typedef _Float16 hv __attribute__((ext_vector_type(2)));

__device__ __forceinline__ hv pkh(float a, float b){
  auto t = __builtin_amdgcn_cvt_pkrtz(a, b);
  hv r; __builtin_memcpy(&r, &t, 4); return r;
}
__device__ __forceinline__ hv bph(int idx4, hv v){
  int s; __builtin_memcpy(&s, &v, 4);
  const int r = __builtin_amdgcn_ds_bpermute(idx4, s);
  hv o; __builtin_memcpy(&o, &r, 4); return o;
}
__device__ __forceinline__ hv swph(hv v){
  u32 u; __builtin_memcpy(&u, &v, 4);
  u = (u >> 16) | (u << 16);
  hv o; __builtin_memcpy(&o, &u, 4); return o;
}
// raw stats: sd += 2*(h.f-h.o)^2 ; sr += h.f^2+h.o^2  (normalized in fss_final)
__device__ __forceinline__ void dstat(hv h, float& sd, float& sr){
  const hv d = h - swph(h);
  sd = __builtin_amdgcn_fdot2(d, d, sd, false);
  sr = __builtin_amdgcn_fdot2(h, h, sr, false);
}

#if __has_builtin(__builtin_amdgcn_rcpf)
#define RCP(x) __builtin_amdgcn_rcpf(x)
#else
#define RCP(x) (1.0f/(x))
#endif
#if __has_builtin(__builtin_amdgcn_exp2f)
#define EXP2(x) __builtin_amdgcn_exp2f(x)
#else
#define EXP2(x) exp2f(x)
#endif

__global__ __launch_bounds__(192) void fss_fused(
    const float* __restrict__ F_, const float* __restrict__ O_,
    double* __restrict__ accum)
{
  const int tid = threadIdx.x;
  const int ln  = tid & 63;
  const int t   = tid >> 6;                    // threshold index = wave id
  const int b   = blockIdx.x;
  const int s   = b % NSTRIP;
  const int rem = b / NSTRIP;
  const int band = rem & (NBAND-1);
  const int img  = rem / NBAND;
  const int y0 = band * BAND;
  const int xbase = 96*s - 16;
  const int x0 = xbase + 2*ln;
  const bool act = (ln >= 8) && (ln < 56) && ((unsigned)x0 < WW);

  // sig_t(v) = rcp(1 + e*K_t), e = exp2(-L10*v); obs_t = bit t of staged mask
  const float K = (t==0) ? 1.0f : ((t==1) ? 148.41315910257660f : 22026.465794806718f);

  const float* F = F_ + (size_t)img*HH*WW;
  const float* O = O_ + (size_t)img*HH*WW;

  __shared__ float          ldse[RING][128];   // e = exp2(-L10*fcst), f32
  __shared__ unsigned short ldso[RING][64];    // obs bits: lo byte col even, hi byte col odd

  // stage row r into ring slot (wave0: e of F; wave1: obs bits of O; wave2 idle)
  auto stage = [&](int r){
    const int slot = (r + RING) % RING;
    const int c = xbase + 2*ln;
    const bool ok = ((unsigned)r < HH) && ((unsigned)c < WW);
    if (t == 0){
      float2 v = {NEGBIG, NEGBIG};
      if (ok) v = *(const float2*)&F[(size_t)r*WW + c];
      float2 e;
      e.x = EXP2(-L10 * v.x);                  // OOB -> +inf -> sig = 0
      e.y = EXP2(-L10 * v.y);
      *(float2*)&ldse[slot][2*ln] = e;
    } else if (t == 1){
      float2 v = {NEGBIG, NEGBIG};
      if (ok) v = *(const float2*)&O[(size_t)r*WW + c];
      const u32 b0 = (u32)(v.x>0.f) | ((u32)(v.x>0.5f)<<1) | ((u32)(v.x>1.f)<<2);
      const u32 b1 = (u32)(v.y>0.f) | ((u32)(v.y>0.5f)<<1) | ((u32)(v.y>1.f)<<2);
      ldso[slot][ln] = (unsigned short)(b0 | (b1 << 8));
    }
  };

  // single-threshold vertical window state + raw stats
  float c9f0=0, c9f1=0, c9o0=0, c9o1=0, c33f0=0, c33f1=0, c33o0=0, c33o1=0;
  float s1d=0, s1r=0, s9d=0, s9r=0, s33d=0, s33r=0;

  const int i_m1=((ln-1)&63)<<2, i_m2=((ln-2)&63)<<2, i_m4=((ln-4)&63)<<2, i_m8=((ln-8)&63)<<2;
  const int i_p1=((ln+1)&63)<<2, i_p2=((ln+2)&63)<<2, i_p7=((ln+7)&63)<<2, i_p8=((ln+8)&63)<<2;

  const u32 bm0 = 1u << t, bm1 = 0x100u << t;

  // ---- prologue: stage rows y0-16 .. y0+17 (34 rows) ----
  #pragma unroll 1
  for (int r = y0-16; r <= y0+17; ++r) stage(r);
  __syncthreads();

  // ---- warmup from ring: rows y0-16 .. y0+16 ----
  #pragma unroll 1
  for (int r = y0-16; r <= y0+16; ++r){
    const int slot = (r + RING) % RING;
    const float2 e2 = *(const float2*)&ldse[slot][2*ln];
    const u32 ob = ldso[slot][ln];
    const float sf0 = RCP(__builtin_fmaf(e2.x, K, 1.0f));
    const float sf1 = RCP(__builtin_fmaf(e2.y, K, 1.0f));
    const float so0 = (ob & bm0) ? 1.f : 0.f;
    const float so1 = (ob & bm1) ? 1.f : 0.f;
    c33f0 += sf0; c33f1 += sf1; c33o0 += so0; c33o1 += so1;
    if (r >= y0-4 && r <= y0+4){ c9f0 += sf0; c9f1 += sf1; c9o0 += so0; c9o1 += so1; }
    if (r >= y0 && r <= y0+4){
      const float d0 = sf0-so0, d1 = sf1-so1;
      s1d += d0*d0 + d1*d1;
      s1r += sf0*sf0 + so0 + sf1*sf1 + so1;    // so^2 == so
    }
  }

  // ---- main loop: 1 barrier/row; ring slot (y+18) written after slide ----
  #pragma unroll 1
  for (int y = y0; y < y0 + BAND; ++y){
    // issue next-row global load early (latency hides under hstats)
    const int rs = y + 18;
    const int wslot = (rs + RING) % RING;
    float2 vst = {NEGBIG, NEGBIG};
    {
      const int c = xbase + 2*ln;
      if (t <= 1 && (unsigned)rs < HH && (unsigned)c < WW)
        vst = *(const float2*)&((t==0) ? F : O)[(size_t)rs*WW + c];
    }

    // horizontal windows + raw stats for row y
    {
      hv wv = pkh(c33f0 + c33f1, c33o0 + c33o1);
      wv = wv + bph(i_m1, wv);
      wv = wv + bph(i_m2, wv);
      wv = wv + bph(i_m4, wv);
      wv = wv + bph(i_m8, wv);
      const hv c0 = pkh(c33f0, c33o0);
      const hv c1 = pkh(c33f1, c33o1);
      const hv h33_0 = bph(i_p7, wv) + bph(i_p8, c0);
      const hv h33_1 = bph(i_p8, wv) + bph(i_m8, c1);

      const hv q  = pkh(c9f0 + c9f1, c9o0 + c9o1);
      const hv q0 = pkh(c9f0, c9o0);
      const hv q1 = pkh(c9f1, c9o1);
      const hv mid = q + bph(i_m1, q) + bph(i_p1, q);
      const hv h9_0 = mid + bph(i_m2, q) + bph(i_p2, q0);
      const hv h9_1 = mid + bph(i_p2, q) + bph(i_m2, q1);

      dstat(h9_0,  s9d,  s9r);
      dstat(h9_1,  s9d,  s9r);
      dstat(h33_0, s33d, s33r);
      dstat(h33_1, s33d, s33r);
    }

    // slide vertical windows to center y+1 from ring
    {
      const int si9  = (y+5)  % RING;
      const int so9  = (y-4  + RING) % RING;
      const int si33 = (y+17) % RING;
      const int so33 = (y-16 + RING) % RING;

      { // entering 9-row (+ k=1 stats)
        const float2 e2 = *(const float2*)&ldse[si9][2*ln];
        const u32 ob = ldso[si9][ln];
        const float sf0 = RCP(__builtin_fmaf(e2.x, K, 1.0f));
        const float sf1 = RCP(__builtin_fmaf(e2.y, K, 1.0f));
        const float so0 = (ob & bm0) ? 1.f : 0.f;
        const float so1 = (ob & bm1) ? 1.f : 0.f;
        c9f0 += sf0; c9f1 += sf1; c9o0 += so0; c9o1 += so1;
        if (y+5 < y0 + BAND){
          const float d0 = sf0-so0, d1 = sf1-so1;
          s1d += d0*d0 + d1*d1;
          s1r += sf0*sf0 + so0 + sf1*sf1 + so1;
        }
      }
      { // leaving 9-row
        const float2 e2 = *(const float2*)&ldse[so9][2*ln];
        const u32 ob = ldso[so9][ln];
        c9f0 -= RCP(__builtin_fmaf(e2.x, K, 1.0f));
        c9f1 -= RCP(__builtin_fmaf(e2.y, K, 1.0f));
        c9o0 -= (ob & bm0) ? 1.f : 0.f;
        c9o1 -= (ob & bm1) ? 1.f : 0.f;
      }
      { // entering 33-row
        const float2 e2 = *(const float2*)&ldse[si33][2*ln];
        const u32 ob = ldso[si33][ln];
        c33f0 += RCP(__builtin_fmaf(e2.x, K, 1.0f));
        c33f1 += RCP(__builtin_fmaf(e2.y, K, 1.0f));
        c33o0 += (ob & bm0) ? 1.f : 0.f;
        c33o1 += (ob & bm1) ? 1.f : 0.f;
      }
      { // leaving 33-row
        const float2 e2 = *(const float2*)&ldse[so33][2*ln];
        const u32 ob = ldso[so33][ln];
        c33f0 -= RCP(__builtin_fmaf(e2.x, K, 1.0f));
        c33f1 -= RCP(__builtin_fmaf(e2.y, K, 1.0f));
        c33o0 -= (ob & bm0) ? 1.f : 0.f;
        c33o1 -= (ob & bm1) ? 1.f : 0.f;
      }
    }

    // write the staged row (slot last read at iter y-1; barrier orders next reads)
    if (t == 0){
      float2 e;
      e.x = EXP2(-L10 * vst.x);
      e.y = EXP2(-L10 * vst.y);
      *(float2*)&ldse[wslot][2*ln] = e;
    } else if (t == 1){
      const u32 b0 = (u32)(vst.x>0.f) | ((u32)(vst.x>0.5f)<<1) | ((u32)(vst.x>1.f)<<2);
      const u32 b1 = (u32)(vst.y>0.f) | ((u32)(vst.y>0.5f)<<1) | ((u32)(vst.y>1.f)<<2);
      ldso[wslot][ln] = (unsigned short)(b0 | (b1 << 8));
    }
    __syncthreads();
  }

  // ---- mask halo lanes, wave-reduce, per-wave f64 atomics ----
  if (!act){ s1d=0; s1r=0; s9d=0; s9r=0; s33d=0; s33r=0; }
  #define WRED(v) { _Pragma("unroll") \
    for (int d = 32; d; d >>= 1) v += __shfl_down(v, (unsigned)d, 64); }
  WRED(s1d);  WRED(s1r);
  WRED(s9d);  WRED(s9r);
  WRED(s33d); WRED(s33r);
  if (ln == 0){
    double* a = accum + (size_t)(img*NTH + t)*6;
    atomicAdd(&a[0], (double)s1d);
    atomicAdd(&a[1], (double)s1r);
    atomicAdd(&a[2], (double)s9d);
    atomicAdd(&a[3], (double)s9r);
    atomicAdd(&a[4], (double)s33d);
    atomicAdd(&a[5], (double)s33r);
  }
}

__global__ void fss_final(const double* __restrict__ accum, float* __restrict__ out)
{
  if (threadIdx.x == 0 && blockIdx.x == 0){
    const double HW = (double)HH * (double)WW;
    const double msc[3] = {1.0, 2.0*6561.0, 2.0*1185921.0};
    const double rsc[3] = {1.0, 6561.0, 1185921.0};
    double total = 0.0;
    for (int t = 0; t < NTH; ++t){
      for (int k = 0; k < 3; ++k){
        double sum = 0.0;
        for (int img = 0; img < NB; ++img){
          const double* a = accum + (size_t)(img*NTH + t)*6 + (size_t)k*2;
          const double mse  = a[0] / (msc[k]*HW);
          const double mref = a[1] / (rsc[k]*HW);
          sum += 1.0 - mse / (mref + 1e-8);
        }
        total += sum / (double)NB;
      }
    }
    out[0] = (float)(1.0 - total/9.0);
  }
}

extern "C" void kernel_launch(void* const* d_in, const int* in_sizes, int n_in,
                              void* d_out, int out_size, void* d_ws, size_t ws_size,
                              hipStream_t stream)
{
  const float* fcst = (const float*)d_in[0];
  const float* obs  = (const float*)d_in[1];
  float* out = (float*)d_out;
  double* accum = (double*)d_ws;

  const int nblocks = NSTRIP * NBAND * NB;   // 2816 blocks x 3 waves

  hipMemsetAsync(d_ws, 0, ACC_BYTES, stream);
  hipLaunchKernelGGL(fss_fused, dim3(nblocks), dim3(192), 0, stream,
                     fcst, obs, accum);
  hipLaunchKernelGGL(fss_final, dim3(1), dim3(64), 0, stream, accum, out);
}

// Round 15
// 248.098 us; speedup vs baseline: 1.0910x; 1.0910x over previous
//
#include <hip/hip_runtime.h>

#define HH 1024
#define WW 1024
#define NB 16
#define NTH 3
#define BAND 128
#define NBAND (HH/BAND)       // 8
#define NSTRIP 11             // strips of 128 cols, 96-col yield
#define ACC_BYTES 4096
#define NEGBIG -1e30f
#define RING 50               // rows alive: [y-16, y+33]
#define L10 14.426950408889634f   // 10*log2(e)

typedef unsigned int u32;
typedef _Float16 hv __attribute__((ext_vector_type(2)));

__device__ __forceinline__ hv pkh(float a, float b){
  auto t = __builtin_amdgcn_cvt_pkrtz(a, b);
  hv r; __builtin_memcpy(&r, &t, 4); return r;
}
__device__ __forceinline__ hv bph(int idx4, hv v){
  int s; __builtin_memcpy(&s, &v, 4);
  const int r = __builtin_amdgcn_ds_bpermute(idx4, s);
  hv o; __builtin_memcpy(&o, &r, 4); return o;
}
__device__ __forceinline__ hv swph(hv v){
  u32 u; __builtin_memcpy(&u, &v, 4);
  u = (u >> 16) | (u << 16);
  hv o; __builtin_memcpy(&o, &u, 4); return o;
}
// raw stats: sd += 2*(h.f-h.o)^2 ; sr += h.f^2+h.o^2  (normalized in fss_final)
__device__ __forceinline__ void dstat(hv h, float& sd, float& sr){
  const hv d = h - swph(h);
  sd = __builtin_amdgcn_fdot2(d, d, sd, false);
  sr = __builtin_amdgcn_fdot2(h, h, sr, false);
}

#if __has_builtin(__builtin_amdgcn_rcpf)
#define RCP(x) __builtin_amdgcn_rcpf(x)
#else
#define RCP(x) (1.0f/(x))
#endif
#if __has_builtin(__builtin_amdgcn_exp2f)
#define EXP2(x) __builtin_amdgcn_exp2f(x)
#else
#define EXP2(x) exp2f(x)
#endif

__global__ __launch_bounds__(192) void fss_fused(
    const float* __restrict__ F_, const float* __restrict__ O_,
    double* __restrict__ accum)
{
  const int tid = threadIdx.x;
  const int ln  = tid & 63;
  const int t   = tid >> 6;                    // threshold index = wave id
  const int b   = blockIdx.x;
  const int s   = b % NSTRIP;
  const int rem = b / NSTRIP;
  const int band = rem & (NBAND-1);
  const int img  = rem / NBAND;
  const int y0 = band * BAND;
  const int xbase = 96*s - 16;
  const int x0 = xbase + 2*ln;
  const bool colok = ((unsigned)x0 < WW);
  const bool act = (ln >= 8) && (ln < 56) && colok;

  // sig_t(v) = rcp(1 + e*K_t), e = exp2(-L10*v); obs_t = bit t of staged mask
  const float K = (t==0) ? 1.0f : ((t==1) ? 148.41315910257660f : 22026.465794806718f);
  const u32 bm0 = 1u << t, bm1 = 0x100u << t;

  const float* F = F_ + (size_t)img*HH*WW;
  const float* O = O_ + (size_t)img*HH*WW;

  __shared__ float          ldse[RING][128];   // e = exp2(-L10*fcst), f32
  __shared__ unsigned short ldso[RING][64];    // obs bits (lo byte even col, hi odd)

  auto slotof = [](int r){ int m = r % RING; return (m < 0) ? m + RING : m; };

  auto stage_e = [&](int r){
    float2 v = {NEGBIG, NEGBIG};
    if ((unsigned)r < HH && colok) v = *(const float2*)&F[(size_t)r*WW + x0];
    float2 e; e.x = EXP2(-L10 * v.x); e.y = EXP2(-L10 * v.y);   // OOB -> +inf -> sig 0
    *(float2*)&ldse[slotof(r)][2*ln] = e;
  };
  auto stage_o = [&](int r){
    float2 v = {NEGBIG, NEGBIG};
    if ((unsigned)r < HH && colok) v = *(const float2*)&O[(size_t)r*WW + x0];
    const u32 b0 = (u32)(v.x>0.f) | ((u32)(v.x>0.5f)<<1) | ((u32)(v.x>1.f)<<2);
    const u32 b1 = (u32)(v.y>0.f) | ((u32)(v.y>0.5f)<<1) | ((u32)(v.y>1.f)<<2);
    ldso[slotof(r)][ln] = (unsigned short)(b0 | (b1 << 8));
  };

  // single-threshold vertical window state + raw stats
  float c9f0=0, c9f1=0, c9o0=0, c9o1=0, c33f0=0, c33f1=0, c33o0=0, c33o1=0;
  float s1d=0, s1r=0, s9d=0, s9r=0, s33d=0, s33r=0;

  const int i_m1=((ln-1)&63)<<2, i_m2=((ln-2)&63)<<2, i_m4=((ln-4)&63)<<2, i_m8=((ln-8)&63)<<2;
  const int i_p1=((ln+1)&63)<<2, i_p2=((ln+2)&63)<<2, i_p7=((ln+7)&63)<<2, i_p8=((ln+8)&63)<<2;

  // ---- prologue: stage rows y0-16 .. y0+25 (42 rows); 84 tasks over 3 waves ----
  #pragma unroll 1
  for (int k = t; k < 84; k += 3){
    if (k < 42) stage_e(y0-16+k);
    else        stage_o(y0-58+k);
  }
  __syncthreads();

  // ---- warmup from ring: rows y0-16 .. y0+16 ----
  {
    int sw = slotof(y0-16);
    #pragma unroll 1
    for (int r = y0-16; r <= y0+16; ++r){
      const float2 e2 = *(const float2*)&ldse[sw][2*ln];
      const u32 ob = ldso[sw][ln];
      sw++; if (sw == RING) sw = 0;
      const float sf0 = RCP(__builtin_fmaf(e2.x, K, 1.0f));
      const float sf1 = RCP(__builtin_fmaf(e2.y, K, 1.0f));
      const float so0 = (ob & bm0) ? 1.f : 0.f;
      const float so1 = (ob & bm1) ? 1.f : 0.f;
      c33f0 += sf0; c33f1 += sf1; c33o0 += so0; c33o1 += so1;
      if (r >= y0-4 && r <= y0+4){ c9f0 += sf0; c9f1 += sf1; c9o0 += so0; c9o1 += so1; }
      if (r >= y0 && r <= y0+4){
        const float d0 = sf0-so0, d1 = sf1-so1;
        s1d += d0*d0 + d1*d1;
        s1r += sf0*sf0 + so0 + sf1*sf1 + so1;    // so^2 == so
      }
    }
  }

  // ---- main loop: barrier per 8 rows; ring-staged, register-prefetched ----
  int si9 = slotof(y0+5), so9 = slotof(y0-4), si33 = slotof(y0+17), so33 = slotof(y0-16);
  int wrb = slotof(y0+26);

  #pragma unroll 1
  for (int g = y0; g < y0 + BAND; g += 8){
    // prefetch the group's 8 staging rows into registers (waves 0 and 1)
    float2 vst[8];
    if (t <= 1){
      const float* P = (t==0) ? F : O;
      #pragma unroll
      for (int j = 0; j < 8; ++j){
        const int r = g + 26 + j;
        vst[j] = make_float2(NEGBIG, NEGBIG);
        if ((unsigned)r < HH && colok)
          vst[j] = *(const float2*)&P[(size_t)r*WW + x0];
      }
    }

    // 8 compute rows (reads are >=9 slots away from this group's writes)
    #pragma unroll 1
    for (int j = 0; j < 8; ++j){
      const int y = g + j;

      // horizontal windows + raw stats for row y
      {
        hv wv = pkh(c33f0 + c33f1, c33o0 + c33o1);
        wv = wv + bph(i_m1, wv);
        wv = wv + bph(i_m2, wv);
        wv = wv + bph(i_m4, wv);
        wv = wv + bph(i_m8, wv);
        const hv c0 = pkh(c33f0, c33o0);
        const hv c1 = pkh(c33f1, c33o1);
        const hv h33_0 = bph(i_p7, wv) + bph(i_p8, c0);
        const hv h33_1 = bph(i_p8, wv) + bph(i_m8, c1);

        const hv q  = pkh(c9f0 + c9f1, c9o0 + c9o1);
        const hv q0 = pkh(c9f0, c9o0);
        const hv q1 = pkh(c9f1, c9o1);
        const hv mid = q + bph(i_m1, q) + bph(i_p1, q);
        const hv h9_0 = mid + bph(i_m2, q) + bph(i_p2, q0);
        const hv h9_1 = mid + bph(i_p2, q) + bph(i_m2, q1);

        dstat(h9_0,  s9d,  s9r);
        dstat(h9_1,  s9d,  s9r);
        dstat(h33_0, s33d, s33r);
        dstat(h33_1, s33d, s33r);
      }

      // slide vertical windows to center y+1 from ring
      {
        { // entering 9-row (+ k=1 stats)
          const float2 e2 = *(const float2*)&ldse[si9][2*ln];
          const u32 ob = ldso[si9][ln];
          const float sf0 = RCP(__builtin_fmaf(e2.x, K, 1.0f));
          const float sf1 = RCP(__builtin_fmaf(e2.y, K, 1.0f));
          const float so0 = (ob & bm0) ? 1.f : 0.f;
          const float so1 = (ob & bm1) ? 1.f : 0.f;
          c9f0 += sf0; c9f1 += sf1; c9o0 += so0; c9o1 += so1;
          if (y+5 < y0 + BAND){
            const float d0 = sf0-so0, d1 = sf1-so1;
            s1d += d0*d0 + d1*d1;
            s1r += sf0*sf0 + so0 + sf1*sf1 + so1;
          }
        }
        { // leaving 9-row
          const float2 e2 = *(const float2*)&ldse[so9][2*ln];
          const u32 ob = ldso[so9][ln];
          c9f0 -= RCP(__builtin_fmaf(e2.x, K, 1.0f));
          c9f1 -= RCP(__builtin_fmaf(e2.y, K, 1.0f));
          c9o0 -= (ob & bm0) ? 1.f : 0.f;
          c9o1 -= (ob & bm1) ? 1.f : 0.f;
        }
        { // entering 33-row
          const float2 e2 = *(const float2*)&ldse[si33][2*ln];
          const u32 ob = ldso[si33][ln];
          c33f0 += RCP(__builtin_fmaf(e2.x, K, 1.0f));
          c33f1 += RCP(__builtin_fmaf(e2.y, K, 1.0f));
          c33o0 += (ob & bm0) ? 1.f : 0.f;
          c33o1 += (ob & bm1) ? 1.f : 0.f;
        }
        { // leaving 33-row
          const float2 e2 = *(const float2*)&ldse[so33][2*ln];
          const u32 ob = ldso[so33][ln];
          c33f0 -= RCP(__builtin_fmaf(e2.x, K, 1.0f));
          c33f1 -= RCP(__builtin_fmaf(e2.y, K, 1.0f));
          c33o0 -= (ob & bm0) ? 1.f : 0.f;
          c33o1 -= (ob & bm1) ? 1.f : 0.f;
        }
        si9++;  if (si9  == RING) si9  = 0;
        so9++;  if (so9  == RING) so9  = 0;
        si33++; if (si33 == RING) si33 = 0;
        so33++; if (so33 == RING) so33 = 0;
      }
    }

    // write the group's staged rows (slots dead since previous group), then sync
    if (t == 0){
      #pragma unroll
      for (int j = 0; j < 8; ++j){
        int wslt = wrb + j; if (wslt >= RING) wslt -= RING;
        float2 e; e.x = EXP2(-L10 * vst[j].x); e.y = EXP2(-L10 * vst[j].y);
        *(float2*)&ldse[wslt][2*ln] = e;
      }
    } else if (t == 1){
      #pragma unroll
      for (int j = 0; j < 8; ++j){
        int wslt = wrb + j; if (wslt >= RING) wslt -= RING;
        const float2 v = vst[j];
        const u32 b0 = (u32)(v.x>0.f) | ((u32)(v.x>0.5f)<<1) | ((u32)(v.x>1.f)<<2);
        const u32 b1 = (u32)(v.y>0.f) | ((u32)(v.y>0.5f)<<1) | ((u32)(v.y>1.f)<<2);
        ldso[wslt][ln] = (unsigned short)(b0 | (b1 << 8));
      }
    }
    wrb += 8; if (wrb >= RING) wrb -= RING;
    __syncthreads();
  }

  // ---- mask halo lanes, wave-reduce, per-wave f64 atomics ----
  if (!act){ s1d=0; s1r=0; s9d=0; s9r=0; s33d=0; s33r=0; }
  #define WRED(v) { _Pragma("unroll") \
    for (int d = 32; d; d >>= 1) v += __shfl_down(v, (unsigned)d, 64); }
  WRED(s1d);  WRED(s1r);
  WRED(s9d);  WRED(s9r);
  WRED(s33d); WRED(s33r);
  if (ln == 0){
    double* a = accum + (size_t)(img*NTH + t)*6;
    atomicAdd(&a[0], (double)s1d);
    atomicAdd(&a[1], (double)s1r);
    atomicAdd(&a[2], (double)s9d);
    atomicAdd(&a[3], (double)s9r);
    atomicAdd(&a[4], (double)s33d);
    atomicAdd(&a[5], (double)s33r);
  }
}

__global__ void fss_final(const double* __restrict__ accum, float* __restrict__ out)
{
  if (threadIdx.x == 0 && blockIdx.x == 0){
    const double HW = (double)HH * (double)WW;
    const double msc[3] = {1.0, 2.0*6561.0, 2.0*1185921.0};
    const double rsc[3] = {1.0, 6561.0, 1185921.0};
    double total = 0.0;
    for (int t = 0; t < NTH; ++t){
      for (int k = 0; k < 3; ++k){
        double sum = 0.0;
        for (int img = 0; img < NB; ++img){
          const double* a = accum + (size_t)(img*NTH + t)*6 + (size_t)k*2;
          const double mse  = a[0] / (msc[k]*HW);
          const double mref = a[1] / (rsc[k]*HW);
          sum += 1.0 - mse / (mref + 1e-8);
        }
        total += sum / (double)NB;
      }
    }
    out[0] = (float)(1.0 - total/9.0);
  }
}

extern "C" void kernel_launch(void* const* d_in, const int* in_sizes, int n_in,
                              void* d_out, int out_size, void* d_ws, size_t ws_size,
                              hipStream_t stream)
{
  const float* fcst = (const float*)d_in[0];
  const float* obs  = (const float*)d_in[1];
  float* out = (float*)d_out;
  double* accum = (double*)d_ws;

  const int nblocks = NSTRIP * NBAND * NB;   // 1408 blocks x 3 waves

  hipMemsetAsync(d_ws, 0, ACC_BYTES, stream);
  hipLaunchKernelGGL(fss_fused, dim3(nblocks), dim3(192), 0, stream,
                     fcst, obs, accum);
  hipLaunchKernelGGL(fss_final, dim3(1), dim3(64), 0, stream, accum, out);
}

// Round 16
// 224.144 us; speedup vs baseline: 1.2076x; 1.1069x over previous
//
#include <hip/hip_runtime.h>

#define HH 1024
#define WW 1024
#define NB 16
#define NTH 3
#define BAND 128
#define NBAND (HH/BAND)       // 8
#define NSTRIP 11             // strips of 128 cols, 96-col yield
#define ACC_BYTES 4096
#define NEGBIG -1e30f
#define RING 41               // live rows during a group: [g-16, g+24]
#define L10 14.426950408889634f   // 10*log2(e)

typedef unsigned int u32;
typedef _Float16 hv __attribute__((ext_vector_type(2)));

__device__ __forceinline__ hv pkh(float a, float b){
  auto t = __builtin_amdgcn_cvt_pkrtz(a, b);
  hv r; __builtin_memcpy(&r, &t, 4); return r;
}
__device__ __forceinline__ hv bph(int idx4, hv v){
  int s; __builtin_memcpy(&s, &v, 4);
  const int r = __builtin_amdgcn_ds_bpermute(idx4, s);
  hv o; __builtin_memcpy(&o, &r, 4); return o;
}
__device__ __forceinline__ hv swph(hv v){
  u32 u; __builtin_memcpy(&u, &v, 4);
  u = (u >> 16) | (u << 16);
  hv o; __builtin_memcpy(&o, &u, 4); return o;
}
// raw stats: sd += 2*(h.f-h.o)^2 ; sr += h.f^2+h.o^2  (normalized in fss_final)
__device__ __forceinline__ void dstat(hv h, float& sd, float& sr){
  const hv d = h - swph(h);
  sd = __builtin_amdgcn_fdot2(d, d, sd, false);
  sr = __builtin_amdgcn_fdot2(h, h, sr, false);
}

#if __has_builtin(__builtin_amdgcn_rcpf)
#define RCP(x) __builtin_amdgcn_rcpf(x)
#else
#define RCP(x) (1.0f/(x))
#endif
#if __has_builtin(__builtin_amdgcn_exp2f)
#define EXP2(x) __builtin_amdgcn_exp2f(x)
#else
#define EXP2(x) exp2f(x)
#endif

__global__ __launch_bounds__(192) void fss_fused(
    const float* __restrict__ F_, const float* __restrict__ O_,
    double* __restrict__ accum)
{
  const int tid = threadIdx.x;
  const int ln  = tid & 63;
  const int t   = tid >> 6;                    // threshold index = wave id
  const int b   = blockIdx.x;
  const int s   = b % NSTRIP;
  const int rem = b / NSTRIP;
  const int band = rem & (NBAND-1);
  const int img  = rem / NBAND;
  const int y0 = band * BAND;
  const int xbase = 96*s - 16;
  const int x0 = xbase + 2*ln;
  const bool colok = ((unsigned)x0 < WW);
  const bool act = (ln >= 8) && (ln < 56) && colok;

  // sig_t(v) = rcp(1 + e*K_t), e = exp2(-L10*v); obs_t = bit t of staged mask
  const float K = (t==0) ? 1.0f : ((t==1) ? 148.41315910257660f : 22026.465794806718f);
  const u32 bm0 = 1u << t, bm1 = 0x100u << t;

  const float* F = F_ + (size_t)img*HH*WW;
  const float* O = O_ + (size_t)img*HH*WW;

  __shared__ float          ldse[RING][128];   // e = exp2(-L10*fcst), f32
  __shared__ unsigned short ldso[RING][64];    // obs bits (lo byte even col, hi odd)

  auto slotof = [](int r){ int m = r % RING; return (m < 0) ? m + RING : m; };

  auto stage_e = [&](int r){
    float2 v = {NEGBIG, NEGBIG};
    if ((unsigned)r < HH && colok) v = *(const float2*)&F[(size_t)r*WW + x0];
    float2 e; e.x = EXP2(-L10 * v.x); e.y = EXP2(-L10 * v.y);   // OOB -> +inf -> sig 0
    *(float2*)&ldse[slotof(r)][2*ln] = e;
  };
  auto stage_o = [&](int r){
    float2 v = {NEGBIG, NEGBIG};
    if ((unsigned)r < HH && colok) v = *(const float2*)&O[(size_t)r*WW + x0];
    const u32 b0 = (u32)(v.x>0.f) | ((u32)(v.x>0.5f)<<1) | ((u32)(v.x>1.f)<<2);
    const u32 b1 = (u32)(v.y>0.f) | ((u32)(v.y>0.5f)<<1) | ((u32)(v.y>1.f)<<2);
    ldso[slotof(r)][ln] = (unsigned short)(b0 | (b1 << 8));
  };

  // single-threshold vertical window state + raw stats
  float c9f0=0, c9f1=0, c9o0=0, c9o1=0, c33f0=0, c33f1=0, c33o0=0, c33o1=0;
  float s1d=0, s1r=0, s9d=0, s9r=0, s33d=0, s33r=0;

  const int i_m1=((ln-1)&63)<<2, i_m2=((ln-2)&63)<<2, i_m4=((ln-4)&63)<<2, i_m8=((ln-8)&63)<<2;
  const int i_p1=((ln+1)&63)<<2, i_p2=((ln+2)&63)<<2, i_p7=((ln+7)&63)<<2, i_p8=((ln+8)&63)<<2;

  // ---- prologue: stage rows y0-16 .. y0+24 (41 rows); 82 tasks over 3 waves ----
  #pragma unroll 1
  for (int k = t; k < 82; k += 3){
    if (k < 41) stage_e(y0-16+k);
    else        stage_o(y0-57+k);     // y0-16 + (k-41)
  }
  __syncthreads();

  // ---- warmup from ring: rows y0-16 .. y0+16 ----
  {
    int sw = slotof(y0-16);
    #pragma unroll 1
    for (int r = y0-16; r <= y0+16; ++r){
      const float2 e2 = *(const float2*)&ldse[sw][2*ln];
      const u32 ob = ldso[sw][ln];
      sw++; if (sw == RING) sw = 0;
      const float sf0 = RCP(__builtin_fmaf(e2.x, K, 1.0f));
      const float sf1 = RCP(__builtin_fmaf(e2.y, K, 1.0f));
      const float so0 = (ob & bm0) ? 1.f : 0.f;
      const float so1 = (ob & bm1) ? 1.f : 0.f;
      c33f0 += sf0; c33f1 += sf1; c33o0 += so0; c33o1 += so1;
      if (r >= y0-4 && r <= y0+4){ c9f0 += sf0; c9f1 += sf1; c9o0 += so0; c9o1 += so1; }
      if (r >= y0 && r <= y0+4){
        const float d0 = sf0-so0, d1 = sf1-so1;
        s1d += d0*d0 + d1*d1;
        s1r += sf0*sf0 + so0 + sf1*sf1 + so1;    // so^2 == so
      }
    }
  }

  // ---- main loop: {prefetch, compute 8 rows, barrier, write, barrier} ----
  int si9 = slotof(y0+5), so9 = slotof(y0-4), si33 = slotof(y0+17), so33 = slotof(y0-16);
  int wrb = slotof(y0+25);

  #pragma unroll 1
  for (int g = y0; g < y0 + BAND; g += 8){
    // prefetch the group's 8 staging rows (rows g+25..g+32) into registers
    float2 vst[8];
    if (t <= 1){
      const float* P = (t==0) ? F : O;
      #pragma unroll
      for (int j = 0; j < 8; ++j){
        const int r = g + 25 + j;
        vst[j] = make_float2(NEGBIG, NEGBIG);
        if ((unsigned)r < HH && colok)
          vst[j] = *(const float2*)&P[(size_t)r*WW + x0];
      }
    }

    // 8 compute rows (reads rows [g-16, g+24], all resident)
    #pragma unroll 1
    for (int j = 0; j < 8; ++j){
      const int y = g + j;

      // horizontal windows + raw stats for row y
      {
        hv wv = pkh(c33f0 + c33f1, c33o0 + c33o1);
        wv = wv + bph(i_m1, wv);
        wv = wv + bph(i_m2, wv);
        wv = wv + bph(i_m4, wv);
        wv = wv + bph(i_m8, wv);
        const hv c0 = pkh(c33f0, c33o0);
        const hv c1 = pkh(c33f1, c33o1);
        const hv h33_0 = bph(i_p7, wv) + bph(i_p8, c0);
        const hv h33_1 = bph(i_p8, wv) + bph(i_m8, c1);

        const hv q  = pkh(c9f0 + c9f1, c9o0 + c9o1);
        const hv q0 = pkh(c9f0, c9o0);
        const hv q1 = pkh(c9f1, c9o1);
        const hv mid = q + bph(i_m1, q) + bph(i_p1, q);
        const hv h9_0 = mid + bph(i_m2, q) + bph(i_p2, q0);
        const hv h9_1 = mid + bph(i_p2, q) + bph(i_m2, q1);

        dstat(h9_0,  s9d,  s9r);
        dstat(h9_1,  s9d,  s9r);
        dstat(h33_0, s33d, s33r);
        dstat(h33_1, s33d, s33r);
      }

      // slide vertical windows to center y+1 from ring
      {
        { // entering 9-row (+ k=1 stats)
          const float2 e2 = *(const float2*)&ldse[si9][2*ln];
          const u32 ob = ldso[si9][ln];
          const float sf0 = RCP(__builtin_fmaf(e2.x, K, 1.0f));
          const float sf1 = RCP(__builtin_fmaf(e2.y, K, 1.0f));
          const float so0 = (ob & bm0) ? 1.f : 0.f;
          const float so1 = (ob & bm1) ? 1.f : 0.f;
          c9f0 += sf0; c9f1 += sf1; c9o0 += so0; c9o1 += so1;
          if (y+5 < y0 + BAND){
            const float d0 = sf0-so0, d1 = sf1-so1;
            s1d += d0*d0 + d1*d1;
            s1r += sf0*sf0 + so0 + sf1*sf1 + so1;
          }
        }
        { // leaving 9-row
          const float2 e2 = *(const float2*)&ldse[so9][2*ln];
          const u32 ob = ldso[so9][ln];
          c9f0 -= RCP(__builtin_fmaf(e2.x, K, 1.0f));
          c9f1 -= RCP(__builtin_fmaf(e2.y, K, 1.0f));
          c9o0 -= (ob & bm0) ? 1.f : 0.f;
          c9o1 -= (ob & bm1) ? 1.f : 0.f;
        }
        { // entering 33-row
          const float2 e2 = *(const float2*)&ldse[si33][2*ln];
          const u32 ob = ldso[si33][ln];
          c33f0 += RCP(__builtin_fmaf(e2.x, K, 1.0f));
          c33f1 += RCP(__builtin_fmaf(e2.y, K, 1.0f));
          c33o0 += (ob & bm0) ? 1.f : 0.f;
          c33o1 += (ob & bm1) ? 1.f : 0.f;
        }
        { // leaving 33-row
          const float2 e2 = *(const float2*)&ldse[so33][2*ln];
          const u32 ob = ldso[so33][ln];
          c33f0 -= RCP(__builtin_fmaf(e2.x, K, 1.0f));
          c33f1 -= RCP(__builtin_fmaf(e2.y, K, 1.0f));
          c33o0 -= (ob & bm0) ? 1.f : 0.f;
          c33o1 -= (ob & bm1) ? 1.f : 0.f;
        }
        si9++;  if (si9  == RING) si9  = 0;
        so9++;  if (so9  == RING) so9  = 0;
        si33++; if (si33 == RING) si33 = 0;
        so33++; if (so33 == RING) so33 = 0;
      }
    }

    // all waves done reading rows [g-16..g-9]; write their slots, then publish
    __syncthreads();
    if (t == 0){
      #pragma unroll
      for (int j = 0; j < 8; ++j){
        int wslt = wrb + j; if (wslt >= RING) wslt -= RING;
        float2 e; e.x = EXP2(-L10 * vst[j].x); e.y = EXP2(-L10 * vst[j].y);
        *(float2*)&ldse[wslt][2*ln] = e;
      }
    } else if (t == 1){
      #pragma unroll
      for (int j = 0; j < 8; ++j){
        int wslt = wrb + j; if (wslt >= RING) wslt -= RING;
        const float2 v = vst[j];
        const u32 b0 = (u32)(v.x>0.f) | ((u32)(v.x>0.5f)<<1) | ((u32)(v.x>1.f)<<2);
        const u32 b1 = (u32)(v.y>0.f) | ((u32)(v.y>0.5f)<<1) | ((u32)(v.y>1.f)<<2);
        ldso[wslt][ln] = (unsigned short)(b0 | (b1 << 8));
      }
    }
    wrb += 8; if (wrb >= RING) wrb -= RING;
    __syncthreads();
  }

  // ---- mask halo lanes, wave-reduce, per-wave f64 atomics ----
  if (!act){ s1d=0; s1r=0; s9d=0; s9r=0; s33d=0; s33r=0; }
  #define WRED(v) { _Pragma("unroll") \
    for (int d = 32; d; d >>= 1) v += __shfl_down(v, (unsigned)d, 64); }
  WRED(s1d);  WRED(s1r);
  WRED(s9d);  WRED(s9r);
  WRED(s33d); WRED(s33r);
  if (ln == 0){
    double* a = accum + (size_t)(img*NTH + t)*6;
    atomicAdd(&a[0], (double)s1d);
    atomicAdd(&a[1], (double)s1r);
    atomicAdd(&a[2], (double)s9d);
    atomicAdd(&a[3], (double)s9r);
    atomicAdd(&a[4], (double)s33d);
    atomicAdd(&a[5], (double)s33r);
  }
}

__global__ void fss_final(const double* __restrict__ accum, float* __restrict__ out)
{
  if (threadIdx.x == 0 && blockIdx.x == 0){
    const double HW = (double)HH * (double)WW;
    const double msc[3] = {1.0, 2.0*6561.0, 2.0*1185921.0};
    const double rsc[3] = {1.0, 6561.0, 1185921.0};
    double total = 0.0;
    for (int t = 0; t < NTH; ++t){
      for (int k = 0; k < 3; ++k){
        double sum = 0.0;
        for (int img = 0; img < NB; ++img){
          const double* a = accum + (size_t)(img*NTH + t)*6 + (size_t)k*2;
          const double mse  = a[0] / (msc[k]*HW);
          const double mref = a[1] / (rsc[k]*HW);
          sum += 1.0 - mse / (mref + 1e-8);
        }
        total += sum / (double)NB;
      }
    }
    out[0] = (float)(1.0 - total/9.0);
  }
}

extern "C" void kernel_launch(void* const* d_in, const int* in_sizes, int n_in,
                              void* d_out, int out_size, void* d_ws, size_t ws_size,
                              hipStream_t stream)
{
  const float* fcst = (const float*)d_in[0];
  const float* obs  = (const float*)d_in[1];
  float* out = (float*)d_out;
  double* accum = (double*)d_ws;

  const int nblocks = NSTRIP * NBAND * NB;   // 1408 blocks x 3 waves

  hipMemsetAsync(d_ws, 0, ACC_BYTES, stream);
  hipLaunchKernelGGL(fss_fused, dim3(nblocks), dim3(192), 0, stream,
                     fcst, obs, accum);
  hipLaunchKernelGGL(fss_final, dim3(1), dim3(64), 0, stream, accum, out);
}